// Round 10
// baseline (27.103 us; speedup 1.0000x reference)
//
#include <hip/hip_runtime.h>

#define NG 48
#define NC 16
#define NPTS (NG * NG * NG)
#define E2F 7.3890561f
#define NINE_OVER_E2 1.2180176f     // 9/e^2
#define LOG2E 1.44269504f

#define SUBCAP 32       // per-(brick,wave) candidate cap (lambda ~7.4, P(>32) ~ 1e-12)
#define SEGCAP 48       // fallback per-wave segment

__device__ __forceinline__ float sel_r(int ci) {
    return ci == 0 ? 1.52f : ci == 1 ? 1.7f : ci == 2 ? 1.55f : 1.8f;
}
__device__ __forceinline__ int chan_mask(int ci, int f) {
    int c1 = (f == 14) ? 4 : ((f == 15) ? 6 : f + 4);
    if (f == 12 || f == 13) c1 = -1;
    const int c2 = (f == 14) ? 5 : ((f == 15) ? 9 : -1);
    int mask = 1 << ci;
    if (c1 >= 0) mask |= 1 << c1;
    if (c2 >= 0) mask |= 1 << c2;
    return mask;
}

// ===== Kernel A: per-brick candidate build. No LDS, no barriers. =====
// 1728 blocks (one per 4x4x4 brick) x 4 waves; wave w ballot-compacts its
// quarter of the atoms straight to global subsegment (brick,w).
__global__ __launch_bounds__(256)
void build_kernel(const float* __restrict__ coords,
                  const int* __restrict__ ch_idx,
                  const int* __restrict__ fg,
                  float4* __restrict__ segAB,   // [(brick*4+w)*SUBCAP + o] * 2 float4s
                  int* __restrict__ counts, int natoms)
{
    const int t = threadIdx.x, w = t >> 6, l = t & 63;
    const int b = blockIdx.x;                        // 0..1727 linear brick id
    const int bx = b / 144, by = (b / 12) % 12, bz = b % 12;

    const float lox = bx * 2.0f, hix = lox + 1.5f;
    const float loy = by * 2.0f, hiy = loy + 1.5f;
    const float loz = bz * 2.0f, hiz = loz + 1.5f;

    const int quarter = (natoms + 3) >> 2;
    const int a0 = w * quarter;
    const int a1 = min(a0 + quarter, natoms);
    const int segbase = (b * 4 + w) * SUBCAP;

    int cnt = 0;
    #pragma unroll 4
    for (int base = a0; base < a1; base += 64) {
        const int a = base + l;
        bool pred = false;
        float ax = 0.f, ay = 0.f, az = 0.f, r = 1.f, cut = 0.f;
        int ci = 0;
        if (a < a1) {
            ax = coords[3 * a]; ay = coords[3 * a + 1]; az = coords[3 * a + 2];
            ci = ch_idx[a];
            r = sel_r(ci);
            cut = 1.5f * r;
            const float ddx = fmaxf(fmaxf(lox - ax, ax - hix), 0.f);
            const float ddy = fmaxf(fmaxf(loy - ay, ay - hiy), 0.f);
            const float ddz = fmaxf(fmaxf(loz - az, az - hiz), 0.f);
            pred = fmaf(ddx, ddx, fmaf(ddy, ddy, ddz * ddz)) < cut * cut;
        }
        const unsigned long long m = __ballot(pred);
        if (pred) {
            const int o = cnt + __popcll(m & ((1ull << l) - 1ull));
            if (o < SUBCAP) {
                const float r2 = r * r;
                const int f = fg[a];                       // survivors only
                segAB[(segbase + o) * 2 + 0] = make_float4(ax, ay, az, cut);
                segAB[(segbase + o) * 2 + 1] = make_float4(-2.0f * LOG2E / r2,
                                                           4.0f / (E2F * r2),
                                                           12.0f / (E2F * r),
                                                           __int_as_float(chan_mask(ci, f)));
            }
        }
        cnt += __popcll(m);
    }
    if (l == 0) counts[b * 4 + w] = min(cnt, SUBCAP);
}

// ===== Kernel B: gather only. No scan, no refine, no candidate LDS. =====
// Wave w walks subsegment (brick,w) via wave-uniform global broadcast reads
// (1 transaction per read, L2-resident), 1-deep prefetch, 16 reg accumulators.
__global__ __launch_bounds__(256, 8)
void density_kernel(const float4* __restrict__ segAB,
                    const int* __restrict__ counts,
                    float* __restrict__ out)
{
    __shared__ float sRed[4 * NC][64];      // 16 KB only -> 8 blocks/CU

    const int t = threadIdx.x, w = t >> 6, l = t & 63;
    const int bz = blockIdx.x, by = blockIdx.y, bx = blockIdx.z;
    const int b = (bx * 12 + by) * 12 + bz;          // matches build layout

    const int cw = counts[b * 4 + w];                // wave-uniform
    const int segbase = (b * 4 + w) * SUBCAP;

    // lane -> grid point (same 64 points for every wave)
    const int tz = l & 3, ty = (l >> 2) & 3, tx = l >> 4;
    const float px = (bx * 4 + tx) * 0.5f;
    const float py = (by * 4 + ty) * 0.5f;
    const float pz = (bz * 4 + tz) * 0.5f;

    float acc[NC];
    #pragma unroll
    for (int c = 0; c < NC; ++c) acc[c] = 0.0f;

    float4 A0, B0;
    if (cw > 0) { A0 = segAB[segbase * 2]; B0 = segAB[segbase * 2 + 1]; }
    for (int i = 0; i < cw; ++i) {
        float4 A1 = A0, B1 = B0;
        if (i + 1 < cw) {
            A1 = segAB[(segbase + i + 1) * 2];
            B1 = segAB[(segbase + i + 1) * 2 + 1];
        }
        const float dx = px - A0.x;
        const float dy = py - A0.y;
        const float dz = pz - A0.z;
        const float d2 = fmaf(dx, dx, fmaf(dy, dy, dz * dz));
        const float cut2 = A0.w * A0.w;
        const float r2 = cut2 * (4.0f / 9.0f);
        const float d  = sqrtf(d2);
        const float f1 = exp2f(B0.x * d2);                    // exp(-2 d2/r2)
        const float f2 = fmaf(B0.y, d2, fmaf(-B0.z, d, NINE_OVER_E2));
        float val = (d2 < r2) ? f1 : f2;
        val = (d2 < cut2) ? val : 0.0f;
        const int chan = __builtin_amdgcn_readfirstlane(__float_as_int(B0.w));
        #pragma unroll
        for (int c = 0; c < NC; ++c) {
            const float msk = __int_as_float(((chan >> c) & 1) * 0x3f800000);
            acc[c] = fmaf(msk, val, acc[c]);   // branch-free
        }
        A0 = A1; B0 = B1;
    }

    // ---- cross-wave reduce + fused float4 store (verified in R9) ----
    #pragma unroll
    for (int c = 0; c < NC; ++c) sRed[w * NC + c][l] = acc[c];
    __syncthreads();                                   // the ONLY barrier

    const int chl = l >> 4;
    const int xy  = l & 15;
    const int c   = w * 4 + chl;
    float4 s = *(const float4*)&sRed[0 * NC + c][xy * 4];
    const float4 s1 = *(const float4*)&sRed[1 * NC + c][xy * 4];
    const float4 s2 = *(const float4*)&sRed[2 * NC + c][xy * 4];
    const float4 s3 = *(const float4*)&sRed[3 * NC + c][xy * 4];
    s.x += s1.x + s2.x + s3.x;
    s.y += s1.y + s2.y + s3.y;
    s.z += s1.z + s2.z + s3.z;
    s.w += s1.w + s2.w + s3.w;

    const int gx = bx * 4 + (xy >> 2);
    const int gy = by * 4 + (xy & 3);
    const int gz0 = bz * 4;
    *(float4*)&out[c * NPTS + (gx * NG + gy) * NG + gz0] = s;
}

// ===== Fallback: R9 fused single kernel (if workspace too small) =====
__global__ __launch_bounds__(256)
void density_fused_kernel(const float* __restrict__ coords,
                          const int* __restrict__ ch_idx,
                          const int* __restrict__ fg,
                          float* __restrict__ out, int natoms)
{
    __shared__ float4 sA[4 * SEGCAP];
    __shared__ float4 sB[4 * SEGCAP];
    __shared__ float sRed[4 * NC][64];

    const int t = threadIdx.x, w = t >> 6, l = t & 63;
    const int bz = blockIdx.x, by = blockIdx.y, bx = blockIdx.z;

    const float lox = bx * 2.0f, hix = lox + 1.5f;
    const float loy = by * 2.0f, hiy = loy + 1.5f;
    const float loz = bz * 2.0f, hiz = loz + 1.5f;

    const int quarter = (natoms + 3) >> 2;
    const int a0 = w * quarter;
    const int a1 = min(a0 + quarter, natoms);
    int cnt = 0;
    #pragma unroll 4
    for (int base = a0; base < a1; base += 64) {
        const int a = base + l;
        bool pred = false;
        float ax = 0.f, ay = 0.f, az = 0.f, r = 1.f, cut = 0.f;
        int ci = 0;
        if (a < a1) {
            ax = coords[3 * a]; ay = coords[3 * a + 1]; az = coords[3 * a + 2];
            ci = ch_idx[a];
            r = sel_r(ci);
            cut = 1.5f * r;
            const float ddx = fmaxf(fmaxf(lox - ax, ax - hix), 0.f);
            const float ddy = fmaxf(fmaxf(loy - ay, ay - hiy), 0.f);
            const float ddz = fmaxf(fmaxf(loz - az, az - hiz), 0.f);
            pred = fmaf(ddx, ddx, fmaf(ddy, ddy, ddz * ddz)) < cut * cut;
        }
        const unsigned long long m = __ballot(pred);
        if (pred) {
            const int o = cnt + __popcll(m & ((1ull << l) - 1ull));
            if (o < SEGCAP) {
                const float r2 = r * r;
                const int f = fg[a];
                sA[w * SEGCAP + o] = make_float4(ax, ay, az, cut);
                sB[w * SEGCAP + o] = make_float4(-2.0f * LOG2E / r2,
                                                 4.0f / (E2F * r2),
                                                 12.0f / (E2F * r),
                                                 __int_as_float(chan_mask(ci, f)));
            }
        }
        cnt += __popcll(m);
    }
    cnt = min(cnt, SEGCAP);

    const int tz = l & 3, ty = (l >> 2) & 3, tx = l >> 4;
    const float px = (bx * 4 + tx) * 0.5f;
    const float py = (by * 4 + ty) * 0.5f;
    const float pz = (bz * 4 + tz) * 0.5f;

    float acc[NC];
    #pragma unroll
    for (int c = 0; c < NC; ++c) acc[c] = 0.0f;

    const int segbase = w * SEGCAP;
    float4 A0, B0;
    if (cnt > 0) { A0 = sA[segbase]; B0 = sB[segbase]; }
    for (int i = 0; i < cnt; ++i) {
        float4 A1 = A0, B1 = B0;
        if (i + 1 < cnt) { A1 = sA[segbase + i + 1]; B1 = sB[segbase + i + 1]; }
        const float dx = px - A0.x;
        const float dy = py - A0.y;
        const float dz = pz - A0.z;
        const float d2 = fmaf(dx, dx, fmaf(dy, dy, dz * dz));
        const float cut2 = A0.w * A0.w;
        const float r2 = cut2 * (4.0f / 9.0f);
        const float d  = sqrtf(d2);
        const float f1 = exp2f(B0.x * d2);
        const float f2 = fmaf(B0.y, d2, fmaf(-B0.z, d, NINE_OVER_E2));
        float val = (d2 < r2) ? f1 : f2;
        val = (d2 < cut2) ? val : 0.0f;
        const int chan = __builtin_amdgcn_readfirstlane(__float_as_int(B0.w));
        #pragma unroll
        for (int c = 0; c < NC; ++c) {
            const float msk = __int_as_float(((chan >> c) & 1) * 0x3f800000);
            acc[c] = fmaf(msk, val, acc[c]);
        }
        A0 = A1; B0 = B1;
    }

    #pragma unroll
    for (int c = 0; c < NC; ++c) sRed[w * NC + c][l] = acc[c];
    __syncthreads();

    const int chl = l >> 4;
    const int xy  = l & 15;
    const int c   = w * 4 + chl;
    float4 s = *(const float4*)&sRed[0 * NC + c][xy * 4];
    const float4 s1 = *(const float4*)&sRed[1 * NC + c][xy * 4];
    const float4 s2 = *(const float4*)&sRed[2 * NC + c][xy * 4];
    const float4 s3 = *(const float4*)&sRed[3 * NC + c][xy * 4];
    s.x += s1.x + s2.x + s3.x;
    s.y += s1.y + s2.y + s3.y;
    s.z += s1.z + s2.z + s3.z;
    s.w += s1.w + s2.w + s3.w;

    const int gx = bx * 4 + (xy >> 2);
    const int gy = by * 4 + (xy & 3);
    const int gz0 = bz * 4;
    *(float4*)&out[c * NPTS + (gx * NG + gy) * NG + gz0] = s;
}

extern "C" void kernel_launch(void* const* d_in, const int* in_sizes, int n_in,
                              void* d_out, int out_size, void* d_ws, size_t ws_size,
                              hipStream_t stream) {
    (void)n_in; (void)out_size;
    const float* coords = (const float*)d_in[0];
    const int* ch = (const int*)d_in[1];
    const int* fgp = (const int*)d_in[2];
    float* out = (float*)d_out;
    const int natoms = in_sizes[0] / 3;

    const int nbricks = 12 * 12 * 12;                          // 1728
    const size_t cnt_bytes = ((size_t)nbricks * 4 * sizeof(int) + 255) & ~255ull;
    const size_t need = cnt_bytes + (size_t)nbricks * 4 * SUBCAP * 2 * sizeof(float4);
    dim3 grid(12, 12, 12);                                     // (bz, by, bx)

    if (ws_size >= need) {
        int* counts = (int*)d_ws;
        float4* segAB = (float4*)((char*)d_ws + cnt_bytes);
        build_kernel<<<nbricks, 256, 0, stream>>>(coords, ch, fgp, segAB, counts, natoms);
        density_kernel<<<grid, 256, 0, stream>>>(segAB, counts, out);
    } else {
        density_fused_kernel<<<grid, 256, 0, stream>>>(coords, ch, fgp, out, natoms);
    }
}